// Round 14
// baseline (492.609 us; speedup 1.0000x reference)
//
#include <hip/hip_runtime.h>
#include <math.h>

#define N_NODES 100000
#define N_EDGES 1600000
#define UNITS   256
#define NGRAPH  512
#define IN_FEAT 9
#define NB_SCAN ((N_NODES + 255) / 256)   // 391
#define NBUK    ((N_NODES + 255) / 256)   // 391 buckets of 256 dst nodes
#define BCAP    8192                      // bucket capacity (expected ~4092)
#define EPB     4096                      // edges per partition block
#define NPB     ((N_EDGES + EPB - 1) / EPB) // 391

typedef short bf16x8 __attribute__((ext_vector_type(8)));
typedef float f32x4  __attribute__((ext_vector_type(4)));
typedef float f32x2  __attribute__((ext_vector_type(2)));

__device__ __forceinline__ float bflo(unsigned int u) {
  return __builtin_bit_cast(float, u << 16);
}
__device__ __forceinline__ float bfhi(unsigned int u) {
  return __builtin_bit_cast(float, u & 0xffff0000u);
}
__device__ __forceinline__ unsigned short f2bf(float f) {
  unsigned int u = __builtin_bit_cast(unsigned int, f);
  u += 0x7fffu + ((u >> 16) & 1u);   // round-to-nearest-even
  return (unsigned short)(u >> 16);
}

// fast tanh: 1 - 2/(e^2x+1). Exact at +-inf; ~1e-6 abs err (<< fp8/bf16 rounding)
__device__ __forceinline__ float tanhfast(float x) {
  float e = __expf(2.0f * x);
  return 1.0f - 2.0f * __builtin_amdgcn_rcpf(e + 1.0f);
}

// decode 8 fp8 e4m3 (uint2) -> bf16x8 via TRUNCATION (bit-exact: fp8->f32 has
// zero low-16 mantissa bits). 4 cvt_pk + 4 v_perm (~8 VALU vs ~20 with RNE).
__device__ __forceinline__ bf16x8 f8tobf(uint2 q) {
  f32x2 v0 = __builtin_amdgcn_cvt_pk_f32_fp8(q.x, false);
  f32x2 v1 = __builtin_amdgcn_cvt_pk_f32_fp8(q.x, true);
  f32x2 v2 = __builtin_amdgcn_cvt_pk_f32_fp8(q.y, false);
  f32x2 v3 = __builtin_amdgcn_cvt_pk_f32_fp8(q.y, true);
  uint4 r;
  r.x = __builtin_amdgcn_perm(__builtin_bit_cast(unsigned int, v0[1]),
                              __builtin_bit_cast(unsigned int, v0[0]), 0x07060302u);
  r.y = __builtin_amdgcn_perm(__builtin_bit_cast(unsigned int, v1[1]),
                              __builtin_bit_cast(unsigned int, v1[0]), 0x07060302u);
  r.z = __builtin_amdgcn_perm(__builtin_bit_cast(unsigned int, v2[1]),
                              __builtin_bit_cast(unsigned int, v2[0]), 0x07060302u);
  r.w = __builtin_amdgcn_perm(__builtin_bit_cast(unsigned int, v3[1]),
                              __builtin_bit_cast(unsigned int, v3[0]), 0x07060302u);
  return __builtin_bit_cast(bf16x8, r);
}
__device__ __forceinline__ unsigned char f2fp8(float v) {
  return (unsigned char)(__builtin_amdgcn_cvt_pk_fp8_f32(v, v, 0, false) & 0xff);
}

// byte offset into a [rows][64] bf16 LDS tile (128 B rows) with T2 XOR swizzle
__device__ __forceinline__ int swz(int row, int byteInRow) {
  return row * 128 + (byteInRow ^ ((row & 7) << 4));
}

// ============================ bucketed CSR build ============================

__global__ __launch_bounds__(256) void k_part(const int* __restrict__ ei,
                                              int* __restrict__ bcnt,
                                              uint2* __restrict__ bstore) {
  __shared__ int hist[NBUK];
  __shared__ int base[NBUK];
  int tid = threadIdx.x;
  int e0 = blockIdx.x * EPB;
  for (int i = tid; i < NBUK; i += 256) hist[i] = 0;
  __syncthreads();
  #pragma unroll 4
  for (int j = 0; j < EPB / 256; ++j) {
    int e = e0 + j * 256 + tid;
    if (e < N_EDGES) atomicAdd(&hist[ei[N_EDGES + e] >> 8], 1);
  }
  __syncthreads();
  for (int i = tid; i < NBUK; i += 256) {
    int h = hist[i];
    base[i] = h ? atomicAdd(&bcnt[i], h) : 0;   // reserve contiguous chunk
    hist[i] = 0;                                 // reuse as cursor
  }
  __syncthreads();
  #pragma unroll 4
  for (int j = 0; j < EPB / 256; ++j) {
    int e = e0 + j * 256 + tid;
    if (e < N_EDGES) {
      int s = ei[e];
      int d = ei[N_EDGES + e];
      int b = d >> 8;
      int pos = base[b] + atomicAdd(&hist[b], 1);
      bstore[(size_t)b * BCAP + pos] = make_uint2((unsigned)s, (unsigned)d);
    }
  }
}

__global__ __launch_bounds__(256) void k_cnt(const int* __restrict__ bcnt,
                                             const uint2* __restrict__ bstore,
                                             int* __restrict__ cnt) {
  __shared__ int h[256];
  int b = blockIdx.x, tid = threadIdx.x;
  h[tid] = 0;
  __syncthreads();
  int nE = bcnt[b];
  for (int i = tid; i < nE; i += 256)
    atomicAdd(&h[bstore[(size_t)b * BCAP + i].y & 255], 1);
  __syncthreads();
  int node = b * 256 + tid;
  if (node < N_NODES) cnt[node] = h[tid];
}

__global__ __launch_bounds__(256) void k_colfill(const int* __restrict__ bcnt,
                                                 const uint2* __restrict__ bstore,
                                                 const int* __restrict__ row_ptr,
                                                 int* __restrict__ col) {
  __shared__ int cur[256];
  int b = blockIdx.x, tid = threadIdx.x;
  int node = b * 256 + tid;
  cur[tid] = (node < N_NODES) ? row_ptr[node] : 0;
  __syncthreads();
  int nE = bcnt[b];
  for (int i = tid; i < nE; i += 256) {
    uint2 sd = bstore[(size_t)b * BCAP + i];
    int pos = atomicAdd(&cur[sd.y & 255], 1);
    col[pos] = (int)sd.x;
  }
}

__global__ __launch_bounds__(256) void k_bsum(const int* __restrict__ cnt,
                                              int* __restrict__ bsum) {
  __shared__ int wsS[4];
  int b = blockIdx.x, tid = threadIdx.x, lane = tid & 63, w = tid >> 6;
  int idx = b * 256 + tid;
  int s = (idx < N_NODES) ? cnt[idx] : 0;
  #pragma unroll
  for (int m = 32; m >= 1; m >>= 1) s += __shfl_xor(s, m);
  if (lane == 0) wsS[w] = s;
  __syncthreads();
  if (tid == 0) bsum[b] = wsS[0] + wsS[1] + wsS[2] + wsS[3];
}

__global__ __launch_bounds__(512) void k_bscan(int* __restrict__ bsum) {
  __shared__ int wsS[8];
  int tid = threadIdx.x, lane = tid & 63, w = tid >> 6;
  int v = (tid < NB_SCAN) ? bsum[tid] : 0;
  int s = v;
  #pragma unroll
  for (int off = 1; off < 64; off <<= 1) {
    int t = __shfl_up(s, off);
    if (lane >= off) s += t;
  }
  if (lane == 63) wsS[w] = s;
  __syncthreads();
  int woff = 0;
  #pragma unroll
  for (int i = 0; i < 8; ++i) woff += (i < w) ? wsS[i] : 0;
  if (tid < NB_SCAN) bsum[tid] = woff + s - v;   // exclusive
}

// block-local exclusive scan + global offset -> row_ptr ; also dinv (merged)
__global__ __launch_bounds__(256) void k_scan3(const int* __restrict__ cnt,
                                               const int* __restrict__ bsum,
                                               int* __restrict__ row_ptr,
                                               float* __restrict__ dinv) {
  __shared__ int wsS[4];
  int b = blockIdx.x, tid = threadIdx.x, lane = tid & 63, w = tid >> 6;
  int idx = b * 256 + tid;
  int v = (idx < N_NODES) ? cnt[idx] : 0;
  int s = v;
  #pragma unroll
  for (int off = 1; off < 64; off <<= 1) {
    int t = __shfl_up(s, off);
    if (lane >= off) s += t;
  }
  if (lane == 63) wsS[w] = s;
  __syncthreads();
  int woff = 0;
  #pragma unroll
  for (int i = 0; i < 4; ++i) woff += (i < w) ? wsS[i] : 0;
  if (idx < N_NODES) {
    row_ptr[idx] = bsum[b] + woff + s - v;
    dinv[idx] = rsqrtf((float)v + 1.0f);   // +1 self-loop
  }
  if (idx == 0) row_ptr[N_NODES] = N_EDGES;
}

__global__ void k_bounds(const int* __restrict__ batch, int* __restrict__ starts) {
  int g = blockIdx.x * blockDim.x + threadIdx.x;
  if (g > NGRAPH) return;
  if (g == NGRAPH) { starts[g] = N_NODES; return; }
  int lo = 0, hi = N_NODES;
  while (lo < hi) { int m = (lo + hi) >> 1; if (batch[m] < g) lo = m + 1; else hi = m; }
  starts[g] = lo;
}

// ============================ Weight transpose/convert ============================

__global__ void k_cvtW(const float* __restrict__ Ws, const float* __restrict__ fc1_w,
                       unsigned short* __restrict__ Wt) {
  int idx = blockIdx.x * 256 + threadIdx.x;   // < 4*256*256
  int m = idx >> 16;
  int r = idx & 65535;
  int n = r >> 8;
  int k = r & 255;
  const float* src = (m < 3) ? (Ws + (size_t)m * 65536) : fc1_w;
  Wt[idx] = f2bf(src[k * 256 + n]);
}

__global__ void k_cvtW2(const float* __restrict__ fc2_w, unsigned short* __restrict__ Wt2) {
  int idx = blockIdx.x * 256 + threadIdx.x;   // < 32*256
  int n = idx >> 8;
  int k = idx & 255;
  Wt2[idx] = f2bf(fc2_w[k * 32 + n]);
}

__global__ void k_scalex(const float* __restrict__ x, const float* __restrict__ dinv,
                         float* __restrict__ xs) {
  int idx = blockIdx.x * blockDim.x + threadIdx.x;
  if (idx < N_NODES * IN_FEAT) xs[idx] = x[idx] * dinv[idx / IN_FEAT];
}

// ============================ layer 0 ============================

__global__ void k_agg9(const float* __restrict__ xs, const int* __restrict__ row_ptr,
                       const int* __restrict__ col, const float* __restrict__ dinv,
                       float* __restrict__ p0) {
  int n = blockIdx.x * blockDim.x + threadIdx.x;
  if (n >= N_NODES) return;
  float acc[IN_FEAT];
  #pragma unroll
  for (int j = 0; j < IN_FEAT; ++j) acc[j] = xs[n * IN_FEAT + j];
  int beg = row_ptr[n], end = row_ptr[n + 1];
  for (int e = beg; e < end; ++e) {
    int s = col[e];
    #pragma unroll
    for (int j = 0; j < IN_FEAT; ++j) acc[j] += xs[s * IN_FEAT + j];
  }
  float dn = dinv[n];
  #pragma unroll
  for (int j = 0; j < IN_FEAT; ++j) p0[n * IN_FEAT + j] = dn * acc[j];
}

// h8 = fp8( dinv * tanh(p0 @ Win + bin) )   [N,9] x [9,256]
__global__ __launch_bounds__(256) void k_gemm9(const float* __restrict__ p0,
                                               const float* __restrict__ Win,
                                               const float* __restrict__ bin,
                                               const float* __restrict__ scale,
                                               unsigned char* __restrict__ h8) {
  __shared__ float pS[32][IN_FEAT];
  int tid = threadIdx.x;
  int row0 = blockIdx.x * 32;
  for (int i = tid; i < 32 * IN_FEAT; i += 256) {
    int r = i / IN_FEAT;
    pS[r][i % IN_FEAT] = (row0 + r < N_NODES) ? p0[(size_t)row0 * IN_FEAT + i] : 0.0f;
  }
  float wcol[IN_FEAT];
  #pragma unroll
  for (int k = 0; k < IN_FEAT; ++k) wcol[k] = Win[k * UNITS + tid];
  float b = bin[tid];
  __syncthreads();
  for (int r = 0; r < 32; ++r) {
    int gr = row0 + r;
    if (gr >= N_NODES) break;
    float a = b;
    #pragma unroll
    for (int k = 0; k < IN_FEAT; ++k) a += pS[r][k] * wcol[k];
    float v = scale[gr] * tanhfast(a);
    float vn = __shfl_xor(v, 1);
    if ((tid & 1) == 0) {
      unsigned int pk = __builtin_amdgcn_cvt_pk_fp8_f32(v, vn, 0, false);
      *(unsigned short*)(h8 + (size_t)gr * UNITS + tid) = (unsigned short)pk;
    }
  }
}

// ============================ aggregation (fp8 in, fp8 out) ============================

__global__ __launch_bounds__(256) void k_agg256(
    const unsigned int* __restrict__ hs8,   // [N][64] words
    const int* __restrict__ row_ptr, const int* __restrict__ col,
    const float* __restrict__ dinv, unsigned int* __restrict__ p8) {
  int wid = threadIdx.x >> 6;
  int lane = threadIdx.x & 63;
  int n = blockIdx.x * 4 + wid;
  if (n >= N_NODES) return;
  unsigned int q = hs8[(size_t)n * 64 + lane];
  f32x2 lo = __builtin_amdgcn_cvt_pk_f32_fp8(q, false);
  f32x2 hi = __builtin_amdgcn_cvt_pk_f32_fp8(q, true);
  float a0 = lo[0], a1 = lo[1], a2 = hi[0], a3 = hi[1];
  int e = row_ptr[n], end = row_ptr[n + 1];
  for (; e + 8 <= end; e += 8) {          // 8 gathers in flight
    int s[8];
    unsigned int qq[8];
    #pragma unroll
    for (int j = 0; j < 8; ++j) s[j] = col[e + j];
    #pragma unroll
    for (int j = 0; j < 8; ++j) qq[j] = hs8[(size_t)s[j] * 64 + lane];
    #pragma unroll
    for (int j = 0; j < 8; ++j) {
      f32x2 l2 = __builtin_amdgcn_cvt_pk_f32_fp8(qq[j], false);
      f32x2 h2 = __builtin_amdgcn_cvt_pk_f32_fp8(qq[j], true);
      a0 += l2[0]; a1 += l2[1]; a2 += h2[0]; a3 += h2[1];
    }
  }
  if (e + 4 <= end) {
    int s[4];
    unsigned int qq[4];
    #pragma unroll
    for (int j = 0; j < 4; ++j) s[j] = col[e + j];
    #pragma unroll
    for (int j = 0; j < 4; ++j) qq[j] = hs8[(size_t)s[j] * 64 + lane];
    #pragma unroll
    for (int j = 0; j < 4; ++j) {
      f32x2 l2 = __builtin_amdgcn_cvt_pk_f32_fp8(qq[j], false);
      f32x2 h2 = __builtin_amdgcn_cvt_pk_f32_fp8(qq[j], true);
      a0 += l2[0]; a1 += l2[1]; a2 += h2[0]; a3 += h2[1];
    }
    e += 4;
  }
  for (; e < end; ++e) {
    unsigned int q0 = hs8[(size_t)col[e] * 64 + lane];
    f32x2 l2 = __builtin_amdgcn_cvt_pk_f32_fp8(q0, false);
    f32x2 h2 = __builtin_amdgcn_cvt_pk_f32_fp8(q0, true);
    a0 += l2[0]; a1 += l2[1]; a2 += h2[0]; a3 += h2[1];
  }
  float dn = dinv[n];
  unsigned int u = __builtin_amdgcn_cvt_pk_fp8_f32(dn * a0, dn * a1, 0, false);
  u = __builtin_amdgcn_cvt_pk_fp8_f32(dn * a2, dn * a3, u, true);
  p8[(size_t)n * 64 + lane] = u;
}

// ============================ dense GEMM (fp8 A, bf16 W, fp8 out) ============================

__global__ __launch_bounds__(256, 4) void k_gemm_f8(
    const unsigned char* __restrict__ A8,
    const unsigned short* __restrict__ Wt,
    const float* __restrict__ bias,
    const float* __restrict__ scale,   // per-row output scaling (dinv)
    unsigned char* __restrict__ C8,
    int M) {
  __shared__ __align__(16) char lds[33792];   // Bs 32KB; Cs8 16.9KB (reused)
  char* Bs = lds;                             // [256][64] bf16 swizzled
  unsigned char (*Cs8)[264] = (unsigned char(*)[264])lds;  // fp8 epilogue repack

  const int tid = threadIdx.x;
  const int w = tid >> 6;
  const int l = tid & 63;
  const int l15 = l & 15;
  const int blk = l >> 4;
  const int wr = w >> 1, wc = w & 1;
  const int row0 = blockIdx.x * 64;

  const int sr = tid >> 3;
  const int sc = (tid & 7) * 16;

  const unsigned char* aRow[2];
  #pragma unroll
  for (int rf = 0; rf < 2; ++rf) {
    int gr = row0 + 32 * wr + rf * 16 + l15;
    if (gr >= M) gr = M - 1;
    aRow[rf] = A8 + (size_t)gr * UNITS + 8 * blk;
  }

  f32x4 acc[2][8];
  #pragma unroll
  for (int rf = 0; rf < 2; ++rf)
    #pragma unroll
    for (int cf = 0; cf < 8; ++cf) acc[rf][cf] = (f32x4){0.f, 0.f, 0.f, 0.f};

  for (int ks = 0; ks < 4; ++ks) {
    const int k0 = ks * 64;
    if (ks) __syncthreads();
    #pragma unroll
    for (int i = 0; i < 8; ++i) {
      int n = sr + i * 32;
      uint4 v = *(const uint4*)(Wt + (size_t)n * UNITS + k0 + (sc >> 1));
      *(uint4*)(Bs + swz(n, sc)) = v;
    }
    __syncthreads();
    #pragma unroll
    for (int kc = 0; kc < 2; ++kc) {
      bf16x8 a[2];
      #pragma unroll
      for (int rf = 0; rf < 2; ++rf) {
        uint2 q = *(const uint2*)(aRow[rf] + k0 + kc * 32);
        a[rf] = f8tobf(q);
      }
      #pragma unroll
      for (int cf = 0; cf < 8; ++cf) {
        bf16x8 b = *(const bf16x8*)(Bs + swz(128 * wc + cf * 16 + l15, kc * 64 + blk * 16));
        acc[0][cf] = __builtin_amdgcn_mfma_f32_16x16x32_bf16(a[0], b, acc[0][cf], 0, 0, 0);
        acc[1][cf] = __builtin_amdgcn_mfma_f32_16x16x32_bf16(a[1], b, acc[1][cf], 0, 0, 0);
      }
    }
  }

  __syncthreads();                 // Bs free -> reuse as Cs8 (fp8 bytes)
  float dvv[2][4];
  #pragma unroll
  for (int rf = 0; rf < 2; ++rf)
    #pragma unroll
    for (int reg = 0; reg < 4; ++reg) {
      int gr = row0 + 32 * wr + rf * 16 + 4 * blk + reg;
      dvv[rf][reg] = scale[gr < M ? gr : M - 1];
    }
  #pragma unroll
  for (int cf = 0; cf < 8; ++cf) {
    float bcol = bias[128 * wc + cf * 16 + l15];
    #pragma unroll
    for (int rf = 0; rf < 2; ++rf) {
      #pragma unroll
      for (int reg = 0; reg < 4; ++reg) {
        float v = dvv[rf][reg] * tanhfast(acc[rf][cf][reg] + bcol);
        Cs8[32 * wr + rf * 16 + 4 * blk + reg][128 * wc + cf * 16 + l15] = f2fp8(v);
      }
    }
  }
  __syncthreads();
  #pragma unroll
  for (int j = 0; j < 8; ++j) {    // 64 rows x 32 chunks of 8 fp8 (8B stores)
    int flat = tid + j * 256;
    int r = flat >> 5;
    int c = flat & 31;
    int gr = row0 + r;
    if (gr < M) {
      *(uint2*)(C8 + (size_t)gr * UNITS + c * 8) = *(const uint2*)&Cs8[r][c * 8];
    }
  }
}

// ============================ fused tail: L2-GEMM + fc1 + fc2/fc3 -> ns ============================

// T stored fp8 (16KB) -> total LDS 48KB -> 3 blocks/CU.
__global__ __launch_bounds__(256, 3) void k_mlp(
    const unsigned char* __restrict__ A8,
    const unsigned short* __restrict__ WtL2, const float* __restrict__ bL2,
    const unsigned short* __restrict__ Wtfc1, const float* __restrict__ bfc1,
    const unsigned short* __restrict__ Wt2, const float* __restrict__ b2,
    const float* __restrict__ w3, const float* __restrict__ b3,
    float* __restrict__ ns, int M) {
  __shared__ __align__(16) char lds[49152];
  char* T8 = lds;            // [64][256] fp8, 256B rows, XOR-swizzled 16B chunks
  char* Bs = lds + 16384;    // [256][64] bf16, 128B rows, XOR-swizzled

  const int tid = threadIdx.x;
  const int w = tid >> 6;
  const int l = tid & 63;
  const int l15 = l & 15;
  const int blk = l >> 4;
  const int wr = w >> 1, wc = w & 1;
  const int row0 = blockIdx.x * 64;

  const int sr = tid >> 3;
  const int sc = (tid & 7) * 16;

  // ---- stage 1: GEMM1 from global fp8 A ----
  const unsigned char* aRow[2];
  #pragma unroll
  for (int rf = 0; rf < 2; ++rf) {
    int gr = row0 + 32 * wr + rf * 16 + l15;
    if (gr >= M) gr = M - 1;
    aRow[rf] = A8 + (size_t)gr * UNITS + 8 * blk;
  }
  f32x4 acc[2][8];
  #pragma unroll
  for (int rf = 0; rf < 2; ++rf)
    #pragma unroll
    for (int cf = 0; cf < 8; ++cf) acc[rf][cf] = (f32x4){0.f, 0.f, 0.f, 0.f};

  for (int ks = 0; ks < 4; ++ks) {
    const int k0 = ks * 64;
    if (ks) __syncthreads();
    #pragma unroll
    for (int i = 0; i < 8; ++i) {
      int n = sr + i * 32;
      uint4 v = *(const uint4*)(WtL2 + (size_t)n * UNITS + k0 + (sc >> 1));
      *(uint4*)(Bs + swz(n, sc)) = v;
    }
    __syncthreads();
    #pragma unroll
    for (int kc = 0; kc < 2; ++kc) {
      bf16x8 a[2];
      #pragma unroll
      for (int rf = 0; rf < 2; ++rf)
        a[rf] = f8tobf(*(const uint2*)(aRow[rf] + k0 + kc * 32));
      #pragma unroll
      for (int cf = 0; cf < 8; ++cf) {
        bf16x8 b = *(const bf16x8*)(Bs + swz(128 * wc + cf * 16 + l15, kc * 64 + blk * 16));
        acc[0][cf] = __builtin_amdgcn_mfma_f32_16x16x32_bf16(a[0], b, acc[0][cf], 0, 0, 0);
        acc[1][cf] = __builtin_amdgcn_mfma_f32_16x16x32_bf16(a[1], b, acc[1][cf], 0, 0, 0);
      }
    }
  }
  // epilogue1 -> T8 fp8 (T8 untouched so far; readers barrier in stage 2)
  #pragma unroll
  for (int cf = 0; cf < 8; ++cf) {
    float bcol = bL2[128 * wc + cf * 16 + l15];
    #pragma unroll
    for (int rf = 0; rf < 2; ++rf) {
      #pragma unroll
      for (int reg = 0; reg < 4; ++reg) {
        int row = 32 * wr + rf * 16 + 4 * blk + reg;
        int colb = 128 * wc + cf * 16 + l15;   // 1 byte per element
        T8[row * 256 + (colb ^ ((row & 7) << 4))] = f2fp8(tanhfast(acc[rf][cf][reg] + bcol));
      }
    }
  }

  // ---- stage 2: GEMM2 from LDS T8 ----
  #pragma unroll
  for (int rf = 0; rf < 2; ++rf)
    #pragma unroll
    for (int cf = 0; cf < 8; ++cf) acc[rf][cf] = (f32x4){0.f, 0.f, 0.f, 0.f};
  for (int ks = 0; ks < 4; ++ks) {
    const int k0 = ks * 64;
    __syncthreads();   // orders: prior Bs reads + epilogue1 T8 writes
    #pragma unroll
    for (int i = 0; i < 8; ++i) {
      int n = sr + i * 32;
      uint4 v = *(const uint4*)(Wtfc1 + (size_t)n * UNITS + k0 + (sc >> 1));
      *(uint4*)(Bs + swz(n, sc)) = v;
    }
    __syncthreads();
    #pragma unroll
    for (int kc = 0; kc < 2; ++kc) {
      bf16x8 a[2];
      #pragma unroll
      for (int rf = 0; rf < 2; ++rf) {
        int ar = 32 * wr + rf * 16 + l15;
        int kb = k0 + kc * 32 + blk * 8;     // element==byte offset
        a[rf] = f8tobf(*(const uint2*)(T8 + ar * 256 + (kb ^ ((ar & 7) << 4))));
      }
      #pragma unroll
      for (int cf = 0; cf < 8; ++cf) {
        bf16x8 b = *(const bf16x8*)(Bs + swz(128 * wc + cf * 16 + l15, kc * 64 + blk * 16));
        acc[0][cf] = __builtin_amdgcn_mfma_f32_16x16x32_bf16(a[0], b, acc[0][cf], 0, 0, 0);
        acc[1][cf] = __builtin_amdgcn_mfma_f32_16x16x32_bf16(a[1], b, acc[1][cf], 0, 0, 0);
      }
    }
  }

  // barrier: all T8 reads + Bs reads done; overwrite T8 with T2, stage Wt2
  __syncthreads();
  #pragma unroll
  for (int cf = 0; cf < 8; ++cf) {
    float bcol = bfc1[128 * wc + cf * 16 + l15];
    #pragma unroll
    for (int rf = 0; rf < 2; ++rf) {
      #pragma unroll
      for (int reg = 0; reg < 4; ++reg) {
        int row = 32 * wr + rf * 16 + 4 * blk + reg;
        int colb = 128 * wc + cf * 16 + l15;
        T8[row * 256 + (colb ^ ((row & 7) << 4))] = f2fp8(tanhfast(acc[rf][cf][reg] + bcol));
      }
    }
  }
  #pragma unroll
  for (int i = 0; i < 4; ++i) {   // Wt2 [32][256] bf16 -> Bs (swizzled, 512B rows)
    int idx = tid + i * 256;       // ushort8 index
    int row = idx >> 5;
    int c = idx & 31;
    uint4 v = *(const uint4*)(Wt2 + (size_t)row * UNITS + c * 8);
    *(uint4*)(Bs + row * 512 + ((c * 16) ^ ((row & 7) << 4))) = v;
  }
  __syncthreads();

  // ---- stage 3: fc2 + tanh + fc3, rows 16*w .. +15 per wave ----
  f32x4 acc0 = (f32x4){0.f, 0.f, 0.f, 0.f};
  f32x4 acc1 = (f32x4){0.f, 0.f, 0.f, 0.f};
  #pragma unroll
  for (int k0 = 0; k0 < UNITS; k0 += 32) {
    int ar = 16 * w + l15;
    int kb = k0 + blk * 8;
    bf16x8 a  = f8tobf(*(const uint2*)(T8 + ar * 256 + (kb ^ ((ar & 7) << 4))));
    int byte = k0 * 2 + blk * 16;
    bf16x8 b0 = *(const bf16x8*)(Bs + l15 * 512 + (byte ^ ((l15 & 7) << 4)));
    bf16x8 b1 = *(const bf16x8*)(Bs + (16 + l15) * 512 + (byte ^ ((l15 & 7) << 4)));
    acc0 = __builtin_amdgcn_mfma_f32_16x16x32_bf16(a, b0, acc0, 0, 0, 0);
    acc1 = __builtin_amdgcn_mfma_f32_16x16x32_bf16(a, b1, acc1, 0, 0, 0);
  }
  float c0 = b2[l15], c1 = b2[16 + l15];
  float w30 = w3[l15], w31 = w3[16 + l15];
  float b3v = b3[0];
  #pragma unroll
  for (int reg = 0; reg < 4; ++reg) {
    float part = tanhfast(acc0[reg] + c0) * w30 + tanhfast(acc1[reg] + c1) * w31;
    #pragma unroll
    for (int m = 8; m >= 1; m >>= 1) part += __shfl_xor(part, m);
    int gr = row0 + 16 * w + 4 * blk + reg;
    if (l15 == 0 && gr < M) ns[gr] = part + b3v;
  }
}

// one wave per graph: deterministic segment mean + sigmoid
__global__ __launch_bounds__(64) void k_pool(const float* __restrict__ ns,
                                             const int* __restrict__ starts,
                                             float* __restrict__ out) {
  int g = blockIdx.x;
  int lane = threadIdx.x;
  int s = starts[g], e = starts[g + 1];
  float acc = 0.0f;
  for (int i = s + lane; i < e; i += 64) acc += ns[i];
  #pragma unroll
  for (int m = 32; m >= 1; m >>= 1) acc += __shfl_xor(acc, m);
  if (lane == 0) {
    float mean = acc / fmaxf((float)(e - s), 1.0f);
    out[g] = 1.0f / (1.0f + expf(-mean));
  }
}

// ============================ launch ============================

extern "C" void kernel_launch(void* const* d_in, const int* in_sizes, int n_in,
                              void* d_out, int out_size, void* d_ws, size_t ws_size,
                              hipStream_t stream) {
  const float* x     = (const float*)d_in[0];
  const int*   ei    = (const int*)d_in[1];
  const int*   batch = (const int*)d_in[2];
  const float* Win   = (const float*)d_in[3];
  const float* bin_  = (const float*)d_in[4];
  const float* Ws    = (const float*)d_in[5];
  const float* bs    = (const float*)d_in[6];
  const float* fc1_w = (const float*)d_in[7];
  const float* fc1_b = (const float*)d_in[8];
  const float* fc2_w = (const float*)d_in[9];
  const float* fc2_b = (const float*)d_in[10];
  const float* fc3_w = (const float*)d_in[11];
  const float* fc3_b = (const float*)d_in[12];
  float* out = (float*)d_out;

  char* ws = (char*)d_ws;
  size_t off = 0;
  auto alloc = [&](size_t bytes) {
    size_t o = off;
    off = (off + bytes + 255) & ~(size_t)255;
    return o;
  };
  int*   cnt     = (int*)(ws + alloc(N_NODES * 4));
  int*   row_ptr = (int*)(ws + alloc((N_NODES + 1) * 4));
  float* dinv    = (float*)(ws + alloc(N_NODES * 4));
  int*   col     = (int*)(ws + alloc((size_t)N_EDGES * 4));
  int*   bsum    = (int*)(ws + alloc(NB_SCAN * 4));
  int*   bcnt    = (int*)(ws + alloc(NBUK * 4));
  uint2* bstore  = (uint2*)(ws + alloc((size_t)NBUK * BCAP * 8));
  int*   starts  = (int*)(ws + alloc((NGRAPH + 1) * 4));
  float* ns      = (float*)(ws + alloc(N_NODES * 4));
  float* xs      = (float*)(ws + alloc((size_t)N_NODES * IN_FEAT * 4));
  float* p0      = (float*)(ws + alloc((size_t)N_NODES * IN_FEAT * 4));
  unsigned short* Wt   = (unsigned short*)(ws + alloc((size_t)4 * UNITS * UNITS * 2));
  unsigned short* Wt2  = (unsigned short*)(ws + alloc((size_t)32 * UNITS * 2));
  unsigned char*  h8a  = (unsigned char*)(ws + alloc((size_t)N_NODES * UNITS));
  unsigned char*  h8b  = (unsigned char*)(ws + alloc((size_t)N_NODES * UNITS));
  unsigned char*  p8   = (unsigned char*)(ws + alloc((size_t)N_NODES * UNITS));

  hipMemsetAsync(bcnt, 0, NBUK * 4, stream);

  // weights -> bf16 transposed
  k_cvtW<<<(4 * UNITS * UNITS) / 256, 256, 0, stream>>>(Ws, fc1_w, Wt);
  k_cvtW2<<<32, 256, 0, stream>>>(fc2_w, Wt2);

  // bucketed CSR build + hierarchical scan (+dinv) + per-graph segment bounds
  k_part<<<NPB, 256, 0, stream>>>(ei, bcnt, bstore);
  k_cnt<<<NBUK, 256, 0, stream>>>(bcnt, bstore, cnt);
  k_bsum<<<NB_SCAN, 256, 0, stream>>>(cnt, bsum);
  k_bscan<<<1, 512, 0, stream>>>(bsum);
  k_scan3<<<NB_SCAN, 256, 0, stream>>>(cnt, bsum, row_ptr, dinv);
  k_colfill<<<NBUK, 256, 0, stream>>>(bcnt, bstore, row_ptr, col);
  k_bounds<<<3, 256, 0, stream>>>(batch, starts);

  // layer 0: pre-scale x, aggregate 9 f32 feats, GEMM 9->256 + tanh -> fp8 (scaled)
  k_scalex<<<(N_NODES * IN_FEAT + 255) / 256, 256, 0, stream>>>(x, dinv, xs);
  k_agg9<<<(N_NODES + 255) / 256, 256, 0, stream>>>(xs, row_ptr, col, dinv, p0);
  k_gemm9<<<(N_NODES + 31) / 32, 256, 0, stream>>>(p0, Win, bin_, dinv, h8a);

  int ggrid = (N_NODES + 63) / 64;
  // L0: agg(h8a)->p8 ; gemm -> h8b (scaled)
  k_agg256<<<(N_NODES + 3) / 4, 256, 0, stream>>>((const unsigned int*)h8a, row_ptr, col, dinv, (unsigned int*)p8);
  k_gemm_f8<<<ggrid, 256, 0, stream>>>(p8, Wt + (size_t)0 * UNITS * UNITS,
                                       bs + (size_t)0 * UNITS, dinv, h8b, N_NODES);
  // L1: agg(h8b)->p8 ; gemm -> h8a (scaled)
  k_agg256<<<(N_NODES + 3) / 4, 256, 0, stream>>>((const unsigned int*)h8b, row_ptr, col, dinv, (unsigned int*)p8);
  k_gemm_f8<<<ggrid, 256, 0, stream>>>(p8, Wt + (size_t)1 * UNITS * UNITS,
                                       bs + (size_t)1 * UNITS, dinv, h8a, N_NODES);
  // L2: agg(h8a)->p8 ; fused L2-GEMM + fc1 + fc2/fc3 -> ns
  k_agg256<<<(N_NODES + 3) / 4, 256, 0, stream>>>((const unsigned int*)h8a, row_ptr, col, dinv, (unsigned int*)p8);
  k_mlp<<<ggrid, 256, 0, stream>>>(p8, Wt + (size_t)2 * UNITS * UNITS,
                                   bs + (size_t)2 * UNITS,
                                   Wt + (size_t)3 * UNITS * UNITS, fc1_b,
                                   Wt2, fc2_b, fc3_w, fc3_b, ns, N_NODES);

  // segment mean + sigmoid
  k_pool<<<NGRAPH, 64, 0, stream>>>(ns, starts, out);
}

// Round 15
// 482.235 us; speedup vs baseline: 1.0215x; 1.0215x over previous
//
#include <hip/hip_runtime.h>
#include <math.h>

#define N_NODES 100000
#define N_EDGES 1600000
#define UNITS   256
#define NGRAPH  512
#define IN_FEAT 9
#define NB_SCAN ((N_NODES + 255) / 256)   // 391
#define NBUK    ((N_NODES + 255) / 256)   // 391 buckets of 256 dst nodes
#define BCAP    8192                      // bucket capacity (expected ~4092)
#define EPB     4096                      // edges per partition block
#define NPB     ((N_EDGES + EPB - 1) / EPB) // 391

typedef short bf16x8 __attribute__((ext_vector_type(8)));
typedef float f32x4  __attribute__((ext_vector_type(4)));
typedef float f32x2  __attribute__((ext_vector_type(2)));

__device__ __forceinline__ float bflo(unsigned int u) {
  return __builtin_bit_cast(float, u << 16);
}
__device__ __forceinline__ float bfhi(unsigned int u) {
  return __builtin_bit_cast(float, u & 0xffff0000u);
}
__device__ __forceinline__ unsigned short f2bf(float f) {
  unsigned int u = __builtin_bit_cast(unsigned int, f);
  u += 0x7fffu + ((u >> 16) & 1u);   // round-to-nearest-even
  return (unsigned short)(u >> 16);
}

// fast tanh: 1 - 2/(e^2x+1). Exact at +-inf; ~1e-6 abs err (<< fp8/bf16 rounding)
__device__ __forceinline__ float tanhfast(float x) {
  float e = __expf(2.0f * x);
  return 1.0f - 2.0f * __builtin_amdgcn_rcpf(e + 1.0f);
}

// decode 8 fp8 e4m3 (uint2) -> bf16x8 ; fp8->f32->bf16 is LOSSLESS (e4m3 c bf16)
__device__ __forceinline__ bf16x8 f8tobf(uint2 q) {
  f32x2 v0 = __builtin_amdgcn_cvt_pk_f32_fp8(q.x, false);
  f32x2 v1 = __builtin_amdgcn_cvt_pk_f32_fp8(q.x, true);
  f32x2 v2 = __builtin_amdgcn_cvt_pk_f32_fp8(q.y, false);
  f32x2 v3 = __builtin_amdgcn_cvt_pk_f32_fp8(q.y, true);
  bf16x8 a;
  a[0] = (short)f2bf(v0[0]); a[1] = (short)f2bf(v0[1]);
  a[2] = (short)f2bf(v1[0]); a[3] = (short)f2bf(v1[1]);
  a[4] = (short)f2bf(v2[0]); a[5] = (short)f2bf(v2[1]);
  a[6] = (short)f2bf(v3[0]); a[7] = (short)f2bf(v3[1]);
  return a;
}
__device__ __forceinline__ unsigned char f2fp8(float v) {
  return (unsigned char)(__builtin_amdgcn_cvt_pk_fp8_f32(v, v, 0, false) & 0xff);
}

// byte offset into a [rows][64] bf16 LDS tile (128 B rows) with T2 XOR swizzle
__device__ __forceinline__ int swz(int row, int byteInRow) {
  return row * 128 + (byteInRow ^ ((row & 7) << 4));
}

// ============================ bucketed CSR build ============================

__global__ __launch_bounds__(256) void k_part(const int* __restrict__ ei,
                                              int* __restrict__ bcnt,
                                              uint2* __restrict__ bstore) {
  __shared__ int hist[NBUK];
  __shared__ int base[NBUK];
  int tid = threadIdx.x;
  int e0 = blockIdx.x * EPB;
  for (int i = tid; i < NBUK; i += 256) hist[i] = 0;
  __syncthreads();
  #pragma unroll 4
  for (int j = 0; j < EPB / 256; ++j) {
    int e = e0 + j * 256 + tid;
    if (e < N_EDGES) atomicAdd(&hist[ei[N_EDGES + e] >> 8], 1);
  }
  __syncthreads();
  for (int i = tid; i < NBUK; i += 256) {
    int h = hist[i];
    base[i] = h ? atomicAdd(&bcnt[i], h) : 0;   // reserve contiguous chunk
    hist[i] = 0;                                 // reuse as cursor
  }
  __syncthreads();
  #pragma unroll 4
  for (int j = 0; j < EPB / 256; ++j) {
    int e = e0 + j * 256 + tid;
    if (e < N_EDGES) {
      int s = ei[e];
      int d = ei[N_EDGES + e];
      int b = d >> 8;
      int pos = base[b] + atomicAdd(&hist[b], 1);
      bstore[(size_t)b * BCAP + pos] = make_uint2((unsigned)s, (unsigned)d);
    }
  }
}

__global__ __launch_bounds__(256) void k_cnt(const int* __restrict__ bcnt,
                                             const uint2* __restrict__ bstore,
                                             int* __restrict__ cnt) {
  __shared__ int h[256];
  int b = blockIdx.x, tid = threadIdx.x;
  h[tid] = 0;
  __syncthreads();
  int nE = bcnt[b];
  for (int i = tid; i < nE; i += 256)
    atomicAdd(&h[bstore[(size_t)b * BCAP + i].y & 255], 1);
  __syncthreads();
  int node = b * 256 + tid;
  if (node < N_NODES) cnt[node] = h[tid];
}

__global__ __launch_bounds__(256) void k_colfill(const int* __restrict__ bcnt,
                                                 const uint2* __restrict__ bstore,
                                                 const int* __restrict__ row_ptr,
                                                 int* __restrict__ col) {
  __shared__ int cur[256];
  int b = blockIdx.x, tid = threadIdx.x;
  int node = b * 256 + tid;
  cur[tid] = (node < N_NODES) ? row_ptr[node] : 0;
  __syncthreads();
  int nE = bcnt[b];
  for (int i = tid; i < nE; i += 256) {
    uint2 sd = bstore[(size_t)b * BCAP + i];
    int pos = atomicAdd(&cur[sd.y & 255], 1);
    col[pos] = (int)sd.x;
  }
}

__global__ __launch_bounds__(256) void k_bsum(const int* __restrict__ cnt,
                                              int* __restrict__ bsum) {
  __shared__ int wsS[4];
  int b = blockIdx.x, tid = threadIdx.x, lane = tid & 63, w = tid >> 6;
  int idx = b * 256 + tid;
  int s = (idx < N_NODES) ? cnt[idx] : 0;
  #pragma unroll
  for (int m = 32; m >= 1; m >>= 1) s += __shfl_xor(s, m);
  if (lane == 0) wsS[w] = s;
  __syncthreads();
  if (tid == 0) bsum[b] = wsS[0] + wsS[1] + wsS[2] + wsS[3];
}

__global__ __launch_bounds__(512) void k_bscan(int* __restrict__ bsum) {
  __shared__ int wsS[8];
  int tid = threadIdx.x, lane = tid & 63, w = tid >> 6;
  int v = (tid < NB_SCAN) ? bsum[tid] : 0;
  int s = v;
  #pragma unroll
  for (int off = 1; off < 64; off <<= 1) {
    int t = __shfl_up(s, off);
    if (lane >= off) s += t;
  }
  if (lane == 63) wsS[w] = s;
  __syncthreads();
  int woff = 0;
  #pragma unroll
  for (int i = 0; i < 8; ++i) woff += (i < w) ? wsS[i] : 0;
  if (tid < NB_SCAN) bsum[tid] = woff + s - v;   // exclusive
}

// block-local exclusive scan + global offset -> row_ptr ; also dinv (merged)
__global__ __launch_bounds__(256) void k_scan3(const int* __restrict__ cnt,
                                               const int* __restrict__ bsum,
                                               int* __restrict__ row_ptr,
                                               float* __restrict__ dinv) {
  __shared__ int wsS[4];
  int b = blockIdx.x, tid = threadIdx.x, lane = tid & 63, w = tid >> 6;
  int idx = b * 256 + tid;
  int v = (idx < N_NODES) ? cnt[idx] : 0;
  int s = v;
  #pragma unroll
  for (int off = 1; off < 64; off <<= 1) {
    int t = __shfl_up(s, off);
    if (lane >= off) s += t;
  }
  if (lane == 63) wsS[w] = s;
  __syncthreads();
  int woff = 0;
  #pragma unroll
  for (int i = 0; i < 4; ++i) woff += (i < w) ? wsS[i] : 0;
  if (idx < N_NODES) {
    row_ptr[idx] = bsum[b] + woff + s - v;
    dinv[idx] = rsqrtf((float)v + 1.0f);   // +1 self-loop
  }
  if (idx == 0) row_ptr[N_NODES] = N_EDGES;
}

__global__ void k_bounds(const int* __restrict__ batch, int* __restrict__ starts) {
  int g = blockIdx.x * blockDim.x + threadIdx.x;
  if (g > NGRAPH) return;
  if (g == NGRAPH) { starts[g] = N_NODES; return; }
  int lo = 0, hi = N_NODES;
  while (lo < hi) { int m = (lo + hi) >> 1; if (batch[m] < g) lo = m + 1; else hi = m; }
  starts[g] = lo;
}

// ============================ Weight transpose/convert ============================

__global__ void k_cvtW(const float* __restrict__ Ws, const float* __restrict__ fc1_w,
                       unsigned short* __restrict__ Wt) {
  int idx = blockIdx.x * 256 + threadIdx.x;   // < 4*256*256
  int m = idx >> 16;
  int r = idx & 65535;
  int n = r >> 8;
  int k = r & 255;
  const float* src = (m < 3) ? (Ws + (size_t)m * 65536) : fc1_w;
  Wt[idx] = f2bf(src[k * 256 + n]);
}

__global__ void k_cvtW2(const float* __restrict__ fc2_w, unsigned short* __restrict__ Wt2) {
  int idx = blockIdx.x * 256 + threadIdx.x;   // < 32*256
  int n = idx >> 8;
  int k = idx & 255;
  Wt2[idx] = f2bf(fc2_w[k * 32 + n]);
}

__global__ void k_scalex(const float* __restrict__ x, const float* __restrict__ dinv,
                         float* __restrict__ xs) {
  int idx = blockIdx.x * blockDim.x + threadIdx.x;
  if (idx < N_NODES * IN_FEAT) xs[idx] = x[idx] * dinv[idx / IN_FEAT];
}

// ============================ layer 0 ============================

__global__ void k_agg9(const float* __restrict__ xs, const int* __restrict__ row_ptr,
                       const int* __restrict__ col, const float* __restrict__ dinv,
                       float* __restrict__ p0) {
  int n = blockIdx.x * blockDim.x + threadIdx.x;
  if (n >= N_NODES) return;
  float acc[IN_FEAT];
  #pragma unroll
  for (int j = 0; j < IN_FEAT; ++j) acc[j] = xs[n * IN_FEAT + j];
  int beg = row_ptr[n], end = row_ptr[n + 1];
  for (int e = beg; e < end; ++e) {
    int s = col[e];
    #pragma unroll
    for (int j = 0; j < IN_FEAT; ++j) acc[j] += xs[s * IN_FEAT + j];
  }
  float dn = dinv[n];
  #pragma unroll
  for (int j = 0; j < IN_FEAT; ++j) p0[n * IN_FEAT + j] = dn * acc[j];
}

// h8 = fp8( dinv * tanh(p0 @ Win + bin) )   [N,9] x [9,256]
__global__ __launch_bounds__(256) void k_gemm9(const float* __restrict__ p0,
                                               const float* __restrict__ Win,
                                               const float* __restrict__ bin,
                                               const float* __restrict__ scale,
                                               unsigned char* __restrict__ h8) {
  __shared__ float pS[32][IN_FEAT];
  int tid = threadIdx.x;
  int row0 = blockIdx.x * 32;
  for (int i = tid; i < 32 * IN_FEAT; i += 256) {
    int r = i / IN_FEAT;
    pS[r][i % IN_FEAT] = (row0 + r < N_NODES) ? p0[(size_t)row0 * IN_FEAT + i] : 0.0f;
  }
  float wcol[IN_FEAT];
  #pragma unroll
  for (int k = 0; k < IN_FEAT; ++k) wcol[k] = Win[k * UNITS + tid];
  float b = bin[tid];
  __syncthreads();
  for (int r = 0; r < 32; ++r) {
    int gr = row0 + r;
    if (gr >= N_NODES) break;
    float a = b;
    #pragma unroll
    for (int k = 0; k < IN_FEAT; ++k) a += pS[r][k] * wcol[k];
    float v = scale[gr] * tanhfast(a);
    float vn = __shfl_xor(v, 1);
    if ((tid & 1) == 0) {
      unsigned int pk = __builtin_amdgcn_cvt_pk_fp8_f32(v, vn, 0, false);
      *(unsigned short*)(h8 + (size_t)gr * UNITS + tid) = (unsigned short)pk;
    }
  }
}

// ============================ aggregation (fp8 in, fp8 out) ============================

__global__ __launch_bounds__(256) void k_agg256(
    const unsigned int* __restrict__ hs8,   // [N][64] words
    const int* __restrict__ row_ptr, const int* __restrict__ col,
    const float* __restrict__ dinv, unsigned int* __restrict__ p8) {
  int wid = threadIdx.x >> 6;
  int lane = threadIdx.x & 63;
  int n = blockIdx.x * 4 + wid;
  if (n >= N_NODES) return;
  unsigned int q = hs8[(size_t)n * 64 + lane];
  f32x2 lo = __builtin_amdgcn_cvt_pk_f32_fp8(q, false);
  f32x2 hi = __builtin_amdgcn_cvt_pk_f32_fp8(q, true);
  float a0 = lo[0], a1 = lo[1], a2 = hi[0], a3 = hi[1];
  int e = row_ptr[n], end = row_ptr[n + 1];
  for (; e + 8 <= end; e += 8) {          // 8 gathers in flight
    int s[8];
    unsigned int qq[8];
    #pragma unroll
    for (int j = 0; j < 8; ++j) s[j] = col[e + j];
    #pragma unroll
    for (int j = 0; j < 8; ++j) qq[j] = hs8[(size_t)s[j] * 64 + lane];
    #pragma unroll
    for (int j = 0; j < 8; ++j) {
      f32x2 l2 = __builtin_amdgcn_cvt_pk_f32_fp8(qq[j], false);
      f32x2 h2 = __builtin_amdgcn_cvt_pk_f32_fp8(qq[j], true);
      a0 += l2[0]; a1 += l2[1]; a2 += h2[0]; a3 += h2[1];
    }
  }
  if (e + 4 <= end) {
    int s[4];
    unsigned int qq[4];
    #pragma unroll
    for (int j = 0; j < 4; ++j) s[j] = col[e + j];
    #pragma unroll
    for (int j = 0; j < 4; ++j) qq[j] = hs8[(size_t)s[j] * 64 + lane];
    #pragma unroll
    for (int j = 0; j < 4; ++j) {
      f32x2 l2 = __builtin_amdgcn_cvt_pk_f32_fp8(qq[j], false);
      f32x2 h2 = __builtin_amdgcn_cvt_pk_f32_fp8(qq[j], true);
      a0 += l2[0]; a1 += l2[1]; a2 += h2[0]; a3 += h2[1];
    }
    e += 4;
  }
  for (; e < end; ++e) {
    unsigned int q0 = hs8[(size_t)col[e] * 64 + lane];
    f32x2 l2 = __builtin_amdgcn_cvt_pk_f32_fp8(q0, false);
    f32x2 h2 = __builtin_amdgcn_cvt_pk_f32_fp8(q0, true);
    a0 += l2[0]; a1 += l2[1]; a2 += h2[0]; a3 += h2[1];
  }
  float dn = dinv[n];
  unsigned int u = __builtin_amdgcn_cvt_pk_fp8_f32(dn * a0, dn * a1, 0, false);
  u = __builtin_amdgcn_cvt_pk_fp8_f32(dn * a2, dn * a3, u, true);
  p8[(size_t)n * 64 + lane] = u;
}

// ============================ dense GEMM (fp8 A, bf16 W, fp8 out) ============================

__global__ __launch_bounds__(256, 4) void k_gemm_f8(
    const unsigned char* __restrict__ A8,
    const unsigned short* __restrict__ Wt,
    const float* __restrict__ bias,
    const float* __restrict__ scale,   // per-row output scaling (dinv)
    unsigned char* __restrict__ C8,
    int M) {
  __shared__ __align__(16) char lds[33792];   // max(Bs 32KB, Cs 33.8KB)
  char* Bs = lds;                             // [256][64] bf16 swizzled
  unsigned short (*Cs)[264] = (unsigned short(*)[264])lds;  // epilogue repack

  const int tid = threadIdx.x;
  const int w = tid >> 6;
  const int l = tid & 63;
  const int l15 = l & 15;
  const int blk = l >> 4;
  const int wr = w >> 1, wc = w & 1;
  const int row0 = blockIdx.x * 64;

  const int sr = tid >> 3;
  const int sc = (tid & 7) * 16;

  const unsigned char* aRow[2];
  #pragma unroll
  for (int rf = 0; rf < 2; ++rf) {
    int gr = row0 + 32 * wr + rf * 16 + l15;
    if (gr >= M) gr = M - 1;
    aRow[rf] = A8 + (size_t)gr * UNITS + 8 * blk;
  }

  f32x4 acc[2][8];
  #pragma unroll
  for (int rf = 0; rf < 2; ++rf)
    #pragma unroll
    for (int cf = 0; cf < 8; ++cf) acc[rf][cf] = (f32x4){0.f, 0.f, 0.f, 0.f};

  for (int ks = 0; ks < 4; ++ks) {
    const int k0 = ks * 64;
    if (ks) __syncthreads();
    #pragma unroll
    for (int i = 0; i < 8; ++i) {
      int n = sr + i * 32;
      uint4 v = *(const uint4*)(Wt + (size_t)n * UNITS + k0 + (sc >> 1));
      *(uint4*)(Bs + swz(n, sc)) = v;
    }
    __syncthreads();
    #pragma unroll
    for (int kc = 0; kc < 2; ++kc) {
      bf16x8 a[2];
      #pragma unroll
      for (int rf = 0; rf < 2; ++rf) {
        uint2 q = *(const uint2*)(aRow[rf] + k0 + kc * 32);
        a[rf] = f8tobf(q);
      }
      #pragma unroll
      for (int cf = 0; cf < 8; ++cf) {
        bf16x8 b = *(const bf16x8*)(Bs + swz(128 * wc + cf * 16 + l15, kc * 64 + blk * 16));
        acc[0][cf] = __builtin_amdgcn_mfma_f32_16x16x32_bf16(a[0], b, acc[0][cf], 0, 0, 0);
        acc[1][cf] = __builtin_amdgcn_mfma_f32_16x16x32_bf16(a[1], b, acc[1][cf], 0, 0, 0);
      }
    }
  }

  __syncthreads();
  float dvv[2][4];
  #pragma unroll
  for (int rf = 0; rf < 2; ++rf)
    #pragma unroll
    for (int reg = 0; reg < 4; ++reg) {
      int gr = row0 + 32 * wr + rf * 16 + 4 * blk + reg;
      dvv[rf][reg] = scale[gr < M ? gr : M - 1];
    }
  #pragma unroll
  for (int cf = 0; cf < 8; ++cf) {
    float bcol = bias[128 * wc + cf * 16 + l15];
    #pragma unroll
    for (int rf = 0; rf < 2; ++rf) {
      #pragma unroll
      for (int reg = 0; reg < 4; ++reg) {
        float v = dvv[rf][reg] * tanhfast(acc[rf][cf][reg] + bcol);
        Cs[32 * wr + rf * 16 + 4 * blk + reg][128 * wc + cf * 16 + l15] = f2bf(v);
      }
    }
  }
  __syncthreads();
  #pragma unroll
  for (int j = 0; j < 8; ++j) {
    int flat = tid + j * 256;
    int r = flat >> 5;
    int c = flat & 31;
    int gr = row0 + r;
    if (gr < M) {
      uint4 v = *(const uint4*)&Cs[r][c * 8];
      uint2 u;
      u.x = __builtin_amdgcn_cvt_pk_fp8_f32(bflo(v.x), bfhi(v.x), 0, false);
      u.x = __builtin_amdgcn_cvt_pk_fp8_f32(bflo(v.y), bfhi(v.y), u.x, true);
      u.y = __builtin_amdgcn_cvt_pk_fp8_f32(bflo(v.z), bfhi(v.z), 0, false);
      u.y = __builtin_amdgcn_cvt_pk_fp8_f32(bflo(v.w), bfhi(v.w), u.y, true);
      *(uint2*)(C8 + (size_t)gr * UNITS + c * 8) = u;
    }
  }
}

// ============================ fused tail: L2-GEMM + fc1 + fc2/fc3 -> ns ============================

// T stored fp8 (16KB) -> total LDS 48KB -> 3 blocks/CU.
__global__ __launch_bounds__(256, 3) void k_mlp(
    const unsigned char* __restrict__ A8,
    const unsigned short* __restrict__ WtL2, const float* __restrict__ bL2,
    const unsigned short* __restrict__ Wtfc1, const float* __restrict__ bfc1,
    const unsigned short* __restrict__ Wt2, const float* __restrict__ b2,
    const float* __restrict__ w3, const float* __restrict__ b3,
    float* __restrict__ ns, int M) {
  __shared__ __align__(16) char lds[49152];
  char* T8 = lds;            // [64][256] fp8, 256B rows, XOR-swizzled 16B chunks
  char* Bs = lds + 16384;    // [256][64] bf16, 128B rows, XOR-swizzled

  const int tid = threadIdx.x;
  const int w = tid >> 6;
  const int l = tid & 63;
  const int l15 = l & 15;
  const int blk = l >> 4;
  const int wr = w >> 1, wc = w & 1;
  const int row0 = blockIdx.x * 64;

  const int sr = tid >> 3;
  const int sc = (tid & 7) * 16;

  // ---- stage 1: GEMM1 from global fp8 A ----
  const unsigned char* aRow[2];
  #pragma unroll
  for (int rf = 0; rf < 2; ++rf) {
    int gr = row0 + 32 * wr + rf * 16 + l15;
    if (gr >= M) gr = M - 1;
    aRow[rf] = A8 + (size_t)gr * UNITS + 8 * blk;
  }
  f32x4 acc[2][8];
  #pragma unroll
  for (int rf = 0; rf < 2; ++rf)
    #pragma unroll
    for (int cf = 0; cf < 8; ++cf) acc[rf][cf] = (f32x4){0.f, 0.f, 0.f, 0.f};

  for (int ks = 0; ks < 4; ++ks) {
    const int k0 = ks * 64;
    if (ks) __syncthreads();
    #pragma unroll
    for (int i = 0; i < 8; ++i) {
      int n = sr + i * 32;
      uint4 v = *(const uint4*)(WtL2 + (size_t)n * UNITS + k0 + (sc >> 1));
      *(uint4*)(Bs + swz(n, sc)) = v;
    }
    __syncthreads();
    #pragma unroll
    for (int kc = 0; kc < 2; ++kc) {
      bf16x8 a[2];
      #pragma unroll
      for (int rf = 0; rf < 2; ++rf)
        a[rf] = f8tobf(*(const uint2*)(aRow[rf] + k0 + kc * 32));
      #pragma unroll
      for (int cf = 0; cf < 8; ++cf) {
        bf16x8 b = *(const bf16x8*)(Bs + swz(128 * wc + cf * 16 + l15, kc * 64 + blk * 16));
        acc[0][cf] = __builtin_amdgcn_mfma_f32_16x16x32_bf16(a[0], b, acc[0][cf], 0, 0, 0);
        acc[1][cf] = __builtin_amdgcn_mfma_f32_16x16x32_bf16(a[1], b, acc[1][cf], 0, 0, 0);
      }
    }
  }
  // epilogue1 -> T8 fp8 (T8 untouched so far; readers barrier in stage 2)
  #pragma unroll
  for (int cf = 0; cf < 8; ++cf) {
    float bcol = bL2[128 * wc + cf * 16 + l15];
    #pragma unroll
    for (int rf = 0; rf < 2; ++rf) {
      #pragma unroll
      for (int reg = 0; reg < 4; ++reg) {
        int row = 32 * wr + rf * 16 + 4 * blk + reg;
        int colb = 128 * wc + cf * 16 + l15;   // 1 byte per element
        T8[row * 256 + (colb ^ ((row & 7) << 4))] = f2fp8(tanhfast(acc[rf][cf][reg] + bcol));
      }
    }
  }

  // ---- stage 2: GEMM2 from LDS T8 ----
  #pragma unroll
  for (int rf = 0; rf < 2; ++rf)
    #pragma unroll
    for (int cf = 0; cf < 8; ++cf) acc[rf][cf] = (f32x4){0.f, 0.f, 0.f, 0.f};
  for (int ks = 0; ks < 4; ++ks) {
    const int k0 = ks * 64;
    __syncthreads();   // orders: prior Bs reads + epilogue1 T8 writes
    #pragma unroll
    for (int i = 0; i < 8; ++i) {
      int n = sr + i * 32;
      uint4 v = *(const uint4*)(Wtfc1 + (size_t)n * UNITS + k0 + (sc >> 1));
      *(uint4*)(Bs + swz(n, sc)) = v;
    }
    __syncthreads();
    #pragma unroll
    for (int kc = 0; kc < 2; ++kc) {
      bf16x8 a[2];
      #pragma unroll
      for (int rf = 0; rf < 2; ++rf) {
        int ar = 32 * wr + rf * 16 + l15;
        int kb = k0 + kc * 32 + blk * 8;     // element==byte offset
        a[rf] = f8tobf(*(const uint2*)(T8 + ar * 256 + (kb ^ ((ar & 7) << 4))));
      }
      #pragma unroll
      for (int cf = 0; cf < 8; ++cf) {
        bf16x8 b = *(const bf16x8*)(Bs + swz(128 * wc + cf * 16 + l15, kc * 64 + blk * 16));
        acc[0][cf] = __builtin_amdgcn_mfma_f32_16x16x32_bf16(a[0], b, acc[0][cf], 0, 0, 0);
        acc[1][cf] = __builtin_amdgcn_mfma_f32_16x16x32_bf16(a[1], b, acc[1][cf], 0, 0, 0);
      }
    }
  }

  // barrier: all T8 reads + Bs reads done; overwrite T8 with T2, stage Wt2
  __syncthreads();
  #pragma unroll
  for (int cf = 0; cf < 8; ++cf) {
    float bcol = bfc1[128 * wc + cf * 16 + l15];
    #pragma unroll
    for (int rf = 0; rf < 2; ++rf) {
      #pragma unroll
      for (int reg = 0; reg < 4; ++reg) {
        int row = 32 * wr + rf * 16 + 4 * blk + reg;
        int colb = 128 * wc + cf * 16 + l15;
        T8[row * 256 + (colb ^ ((row & 7) << 4))] = f2fp8(tanhfast(acc[rf][cf][reg] + bcol));
      }
    }
  }
  #pragma unroll
  for (int i = 0; i < 4; ++i) {   // Wt2 [32][256] bf16 -> Bs (swizzled, 512B rows)
    int idx = tid + i * 256;       // ushort8 index
    int row = idx >> 5;
    int c = idx & 31;
    uint4 v = *(const uint4*)(Wt2 + (size_t)row * UNITS + c * 8);
    *(uint4*)(Bs + row * 512 + ((c * 16) ^ ((row & 7) << 4))) = v;
  }
  __syncthreads();

  // ---- stage 3: fc2 + tanh + fc3, rows 16*w .. +15 per wave ----
  f32x4 acc0 = (f32x4){0.f, 0.f, 0.f, 0.f};
  f32x4 acc1 = (f32x4){0.f, 0.f, 0.f, 0.f};
  #pragma unroll
  for (int k0 = 0; k0 < UNITS; k0 += 32) {
    int ar = 16 * w + l15;
    int kb = k0 + blk * 8;
    bf16x8 a  = f8tobf(*(const uint2*)(T8 + ar * 256 + (kb ^ ((ar & 7) << 4))));
    int byte = k0 * 2 + blk * 16;
    bf16x8 b0 = *(const bf16x8*)(Bs + l15 * 512 + (byte ^ ((l15 & 7) << 4)));
    bf16x8 b1 = *(const bf16x8*)(Bs + (16 + l15) * 512 + (byte ^ ((l15 & 7) << 4)));
    acc0 = __builtin_amdgcn_mfma_f32_16x16x32_bf16(a, b0, acc0, 0, 0, 0);
    acc1 = __builtin_amdgcn_mfma_f32_16x16x32_bf16(a, b1, acc1, 0, 0, 0);
  }
  float c0 = b2[l15], c1 = b2[16 + l15];
  float w30 = w3[l15], w31 = w3[16 + l15];
  float b3v = b3[0];
  #pragma unroll
  for (int reg = 0; reg < 4; ++reg) {
    float part = tanhfast(acc0[reg] + c0) * w30 + tanhfast(acc1[reg] + c1) * w31;
    #pragma unroll
    for (int m = 8; m >= 1; m >>= 1) part += __shfl_xor(part, m);
    int gr = row0 + 16 * w + 4 * blk + reg;
    if (l15 == 0 && gr < M) ns[gr] = part + b3v;
  }
}

// one wave per graph: deterministic segment mean + sigmoid
__global__ __launch_bounds__(64) void k_pool(const float* __restrict__ ns,
                                             const int* __restrict__ starts,
                                             float* __restrict__ out) {
  int g = blockIdx.x;
  int lane = threadIdx.x;
  int s = starts[g], e = starts[g + 1];
  float acc = 0.0f;
  for (int i = s + lane; i < e; i += 64) acc += ns[i];
  #pragma unroll
  for (int m = 32; m >= 1; m >>= 1) acc += __shfl_xor(acc, m);
  if (lane == 0) {
    float mean = acc / fmaxf((float)(e - s), 1.0f);
    out[g] = 1.0f / (1.0f + expf(-mean));
  }
}

// ============================ launch ============================

extern "C" void kernel_launch(void* const* d_in, const int* in_sizes, int n_in,
                              void* d_out, int out_size, void* d_ws, size_t ws_size,
                              hipStream_t stream) {
  const float* x     = (const float*)d_in[0];
  const int*   ei    = (const int*)d_in[1];
  const int*   batch = (const int*)d_in[2];
  const float* Win   = (const float*)d_in[3];
  const float* bin_  = (const float*)d_in[4];
  const float* Ws    = (const float*)d_in[5];
  const float* bs    = (const float*)d_in[6];
  const float* fc1_w = (const float*)d_in[7];
  const float* fc1_b = (const float*)d_in[8];
  const float* fc2_w = (const float*)d_in[9];
  const float* fc2_b = (const float*)d_in[10];
  const float* fc3_w = (const float*)d_in[11];
  const float* fc3_b = (const float*)d_in[12];
  float* out = (float*)d_out;

  char* ws = (char*)d_ws;
  size_t off = 0;
  auto alloc = [&](size_t bytes) {
    size_t o = off;
    off = (off + bytes + 255) & ~(size_t)255;
    return o;
  };
  int*   cnt     = (int*)(ws + alloc(N_NODES * 4));
  int*   row_ptr = (int*)(ws + alloc((N_NODES + 1) * 4));
  float* dinv    = (float*)(ws + alloc(N_NODES * 4));
  int*   col     = (int*)(ws + alloc((size_t)N_EDGES * 4));
  int*   bsum    = (int*)(ws + alloc(NB_SCAN * 4));
  int*   bcnt    = (int*)(ws + alloc(NBUK * 4));
  uint2* bstore  = (uint2*)(ws + alloc((size_t)NBUK * BCAP * 8));
  int*   starts  = (int*)(ws + alloc((NGRAPH + 1) * 4));
  float* ns      = (float*)(ws + alloc(N_NODES * 4));
  float* xs      = (float*)(ws + alloc((size_t)N_NODES * IN_FEAT * 4));
  float* p0      = (float*)(ws + alloc((size_t)N_NODES * IN_FEAT * 4));
  unsigned short* Wt   = (unsigned short*)(ws + alloc((size_t)4 * UNITS * UNITS * 2));
  unsigned short* Wt2  = (unsigned short*)(ws + alloc((size_t)32 * UNITS * 2));
  unsigned char*  h8a  = (unsigned char*)(ws + alloc((size_t)N_NODES * UNITS));
  unsigned char*  h8b  = (unsigned char*)(ws + alloc((size_t)N_NODES * UNITS));
  unsigned char*  p8   = (unsigned char*)(ws + alloc((size_t)N_NODES * UNITS));

  hipMemsetAsync(bcnt, 0, NBUK * 4, stream);

  // weights -> bf16 transposed
  k_cvtW<<<(4 * UNITS * UNITS) / 256, 256, 0, stream>>>(Ws, fc1_w, Wt);
  k_cvtW2<<<32, 256, 0, stream>>>(fc2_w, Wt2);

  // bucketed CSR build + hierarchical scan (+dinv) + per-graph segment bounds
  k_part<<<NPB, 256, 0, stream>>>(ei, bcnt, bstore);
  k_cnt<<<NBUK, 256, 0, stream>>>(bcnt, bstore, cnt);
  k_bsum<<<NB_SCAN, 256, 0, stream>>>(cnt, bsum);
  k_bscan<<<1, 512, 0, stream>>>(bsum);
  k_scan3<<<NB_SCAN, 256, 0, stream>>>(cnt, bsum, row_ptr, dinv);
  k_colfill<<<NBUK, 256, 0, stream>>>(bcnt, bstore, row_ptr, col);
  k_bounds<<<3, 256, 0, stream>>>(batch, starts);

  // layer 0: pre-scale x, aggregate 9 f32 feats, GEMM 9->256 + tanh -> fp8 (scaled)
  k_scalex<<<(N_NODES * IN_FEAT + 255) / 256, 256, 0, stream>>>(x, dinv, xs);
  k_agg9<<<(N_NODES + 255) / 256, 256, 0, stream>>>(xs, row_ptr, col, dinv, p0);
  k_gemm9<<<(N_NODES + 31) / 32, 256, 0, stream>>>(p0, Win, bin_, dinv, h8a);

  int ggrid = (N_NODES + 63) / 64;
  // L0: agg(h8a)->p8 ; gemm -> h8b (scaled)
  k_agg256<<<(N_NODES + 3) / 4, 256, 0, stream>>>((const unsigned int*)h8a, row_ptr, col, dinv, (unsigned int*)p8);
  k_gemm_f8<<<ggrid, 256, 0, stream>>>(p8, Wt + (size_t)0 * UNITS * UNITS,
                                       bs + (size_t)0 * UNITS, dinv, h8b, N_NODES);
  // L1: agg(h8b)->p8 ; gemm -> h8a (scaled)
  k_agg256<<<(N_NODES + 3) / 4, 256, 0, stream>>>((const unsigned int*)h8b, row_ptr, col, dinv, (unsigned int*)p8);
  k_gemm_f8<<<ggrid, 256, 0, stream>>>(p8, Wt + (size_t)1 * UNITS * UNITS,
                                       bs + (size_t)1 * UNITS, dinv, h8a, N_NODES);
  // L2: agg(h8a)->p8 ; fused L2-GEMM + fc1 + fc2/fc3 -> ns
  k_agg256<<<(N_NODES + 3) / 4, 256, 0, stream>>>((const unsigned int*)h8a, row_ptr, col, dinv, (unsigned int*)p8);
  k_mlp<<<ggrid, 256, 0, stream>>>(p8, Wt + (size_t)2 * UNITS * UNITS,
                                   bs + (size_t)2 * UNITS,
                                   Wt + (size_t)3 * UNITS * UNITS, fc1_b,
                                   Wt2, fc2_b, fc3_w, fc3_b, ns, N_NODES);

  // segment mean + sigmoid
  k_pool<<<NGRAPH, 64, 0, stream>>>(ns, starts, out);
}